// Round 10
// baseline (911.698 us; speedup 1.0000x reference)
//
#include <hip/hip_runtime.h>
#include <hip/hip_bf16.h>

typedef short bf16x8 __attribute__((ext_vector_type(8)));
typedef float f32x4 __attribute__((ext_vector_type(4)));

#define LQ 4096
#define DK 576
#define DV 1024

__device__ inline unsigned short f2bf(float x){
    unsigned int u = __float_as_uint(x);
    u += 0x7fffu + ((u>>16)&1u);
    return (unsigned short)(u>>16);
}
__device__ inline float bf2f(unsigned short v){
    return __uint_as_float(((unsigned int)v)<<16);
}

// K1: fd[b,o,y,x] = gb[o] + sum_c f[b,c,2y,2x]*gw[o,c]
__global__ __launch_bounds__(256) void k1_fd(const float* __restrict__ f, const float* __restrict__ gw,
                                             const float* __restrict__ gb, float* __restrict__ fd){
    int y = blockIdx.x, b = blockIdx.y;
    __shared__ float fs[128][64];
    int t = threadIdx.x;
    const float* fbase = f + ((size_t)b*128*128*128) + (size_t)(2*y)*128;
    for(int i=t;i<8192;i+=256){ int c=i>>6, x=i&63; fs[c][x] = fbase[(size_t)c*16384 + 2*x]; }
    __syncthreads();
    int lane = t & 63, w = t >> 6;
    for(int oi=0; oi<16; ++oi){
        int o = w*16 + oi;
        const float* gwr = gw + o*128;
        float acc = gb[o];
        #pragma unroll 8
        for(int c=0;c<128;++c) acc += gwr[c]*fs[c][lane];
        fd[(((size_t)b*64+o)*64+y)*64 + lane] = acc;
    }
}

// K2: Wp[b,p,k] row-major (bf16) + KF fragment-major normalized K.
// KF elem (p,k): pf=p>>4, pl=p&15, kc=k>>5, kh=(k>>3)&3, jj=k&7
//   KF[((((b*256+pf)*18+kc)*64) + kh*16+pl)*8 + jj]
__global__ __launch_bounds__(256) void k2_wp(const float* __restrict__ fd, unsigned short* __restrict__ Wp,
                                             unsigned short* __restrict__ KF){
    int y = blockIdx.x, b = blockIdx.y;
    __shared__ float fds[3][64][64];
    int t = threadIdx.x;
    for(int i=t;i<12288;i+=256){
        int d=i>>12, rem=i&4095, c=rem>>6, x=rem&63;
        int yy = y + d - 1; yy = yy<0 ? 1 : (yy>63 ? 62 : yy);
        fds[d][c][x] = fd[(((size_t)b*64+c)*64+yy)*64 + x];
    }
    __syncthreads();
    int lane = t&63, w = t>>6;
    for(int xi=0; xi<16; ++xi){
        int x = xi*4 + w;
        int p = y*64 + x;
        float vals[9]; float s = 0.f;
        #pragma unroll
        for(int j=0;j<9;++j){
            int k = j*64 + lane;
            int c = k/9, r = k - c*9;
            int dy = r/3, dx = r - dy*3;
            int xx = x + dx - 1; xx = xx<0 ? 1 : (xx>63 ? 62 : xx);
            float v = fds[dy][c][xx];
            vals[j] = v; s += v*v;
        }
        #pragma unroll
        for(int off=32; off>=1; off>>=1) s += __shfl_xor(s, off);
        float nrm = sqrtf(s); if(nrm < 1e-4f) nrm = 1e-4f;
        float sc = 1.f/nrm;
        size_t base = ((size_t)b*LQ + p)*DK;
        int pf = p>>4, pl = p&15;
        #pragma unroll
        for(int j=0;j<9;++j){
            int k = j*64+lane;
            Wp[base+k] = f2bf(vals[j]);
            int kc = k>>5, kh = (k>>3)&3, jj = k&7;
            KF[((((size_t)b*256 + pf)*18 + kc)*64 + kh*16 + pl)*8 + jj] = f2bf(vals[j]*sc);
        }
    }
}

// K3: VF fragment-major V. elem (v,p): pt=p>>6, px=p&63, kc2=px>>5, lhi=(px>>3)&3, jj=px&7,
//   vf=v>>4, vl=v&15:  VF[(((((b*64+pt)*64+vf)*2+kc2)*64)+lhi*16+vl)*8 + jj]
__global__ __launch_bounds__(256) void k3_vf(const float* __restrict__ alpha, unsigned short* __restrict__ VF){
    int py = blockIdx.x, cq = blockIdx.y, b = blockIdx.z;
    __shared__ float als[16][4][128];
    int t = threadIdx.x;
    for(int i=t;i<8192;i+=256){
        int c = i>>9, rem = i&511, rr = rem>>7, x = rem&127;
        int m = 2*py + rr - 1; m = m<0 ? 1 : (m>127 ? 126 : m);
        als[c][rr][x] = alpha[(((size_t)b*64 + cq*16 + c)*128 + m)*128 + x];
    }
    __syncthreads();
    int lane = t&63, w = t>>6;
    int kc2 = lane>>5, lhi = (lane>>3)&3, jj = lane&7;
    for(int vi=0; vi<64; ++vi){
        int vl = w*64 + vi;                 // 0..255 within quarter
        int c = vl>>4, r = vl&15, ky = r>>2, kx = r&3;
        int xx = 2*lane + kx - 1; xx = xx<0 ? 1 : (xx>127 ? 126 : xx);
        float v = als[c][ky][xx];
        int vglob = cq*256 + vl;
        int vf = vglob>>4, vl15 = vglob&15;
        VF[(((((size_t)b*64 + py)*64 + vf)*2 + kc2)*64 + lhi*16 + vl15)*8 + jj] = f2bf(v);
    }
}

// K45d: fused flash attention, fragment-major operands, fixed-max softmax, p-step 256.
// 512 thr = 8 waves. S: wave (qf=w&1, ph=w>>1) computes 16q x 64p (4 strips of 16p).
// PV: wave w handles v-range w*128 (acc 32q x 128v).
__global__ __launch_bounds__(512, 4) void k45d(const unsigned short* __restrict__ Wp,
                                               const unsigned short* __restrict__ KF,
                                               const unsigned short* __restrict__ VF,
                                               unsigned short* __restrict__ att){
    int j = blockIdx.x;
    int xcd = j & 7;
    int b = xcd >> 1;
    int qt = (j >> 3) + ((xcd & 1) << 6);   // 0..127
    int q0 = qt*32;

    int t = threadIdx.x, lane = t&63, w = t>>6;
    int l15 = lane&15, lhi = lane>>4;
    int qf = w&1, ph = w>>1;

    __shared__ unsigned short Qs[32*576];    // 36864 B, XOR-swizzled rows
    __shared__ unsigned short Ps[32*256];    // 16384 B, row stride 512B, XOR-swizzled
    __shared__ float lpart[4][32];

    // stage Q (Wp rows q0..q0+31), coalesced 16B, swizzle per row
    {
        const char* src = (const char*)(Wp + ((size_t)b*LQ + q0)*DK);
        for(int i=t;i<2304;i+=512){
            int row = i/72, c = i%72;
            uint4 v = *(const uint4*)(src + (size_t)row*1152 + c*16);
            *(uint4*)((char*)Qs + row*1152 + ((c*16) ^ ((row&7)<<4))) = v;
        }
    }
    __syncthreads();

    const char* Qrowbase = (const char*)Qs + (qf*16 + l15)*1152;
    int qswz = ((qf*16 + l15)&7)<<4;

    float l_run[4] = {0.f,0.f,0.f,0.f};
    f32x4 acc[2][8];
    #pragma unroll
    for(int qs=0;qs<2;++qs)
        #pragma unroll
        for(int v=0;v<8;++v){ acc[qs][v][0]=0.f; acc[qs][v][1]=0.f; acc[qs][v][2]=0.f; acc[qs][v][3]=0.f; }

    int qg0 = q0 + qf*16 + lhi*4;

    for(int p0=0;p0<LQ;p0+=256){
        // ---- S strip 0 compute (overlaps prev iter's PV; no Ps access) ----
        int pfrag0 = (p0>>4) + ph*4;
        const unsigned short* kf0 = KF + (((size_t)b*256 + pfrag0)*18)*512 + lane*8;
        f32x4 s0a, s0b;
        s0a[0]=0.f;s0a[1]=0.f;s0a[2]=0.f;s0a[3]=0.f;
        s0b[0]=0.f;s0b[1]=0.f;s0b[2]=0.f;s0b[3]=0.f;
        #pragma unroll
        for(int kc=0;kc<18;kc+=2){
            bf16x8 a0 = *(const bf16x8*)(Qrowbase + ((kc*64 + lhi*16) ^ qswz));
            bf16x8 b0 = *(const bf16x8*)(kf0 + kc*512);
            s0a = __builtin_amdgcn_mfma_f32_16x16x32_bf16(a0, b0, s0a, 0,0,0);
            bf16x8 a1 = *(const bf16x8*)(Qrowbase + (((kc+1)*64 + lhi*16) ^ qswz));
            bf16x8 b1 = *(const bf16x8*)(kf0 + (kc+1)*512);
            s0b = __builtin_amdgcn_mfma_f32_16x16x32_bf16(a1, b1, s0b, 0,0,0);
        }
        __syncthreads();   // prev-iter PV reads of Ps complete
        // write strip 0 P
        {
            int pg = pfrag0*16 + l15;
            #pragma unroll
            for(int r=0;r<4;++r){
                float sv = s0a[r] + s0b[r];
                if(pg == qg0 + r) sv -= 10000.f;
                float pv = __expf(sv);
                l_run[r] += pv;
                int row = qf*16 + lhi*4 + r;
                int col = ph*64 + l15;
                *(unsigned short*)((char*)Ps + ((row*512 + col*2) ^ ((row&7)<<4))) = f2bf(pv);
            }
        }
        // ---- S strips 1..3 ----
        #pragma unroll
        for(int s=1;s<4;++s){
            int pfrag = pfrag0 + s;
            const unsigned short* kf = KF + (((size_t)b*256 + pfrag)*18)*512 + lane*8;
            f32x4 sa, sb;
            sa[0]=0.f;sa[1]=0.f;sa[2]=0.f;sa[3]=0.f;
            sb[0]=0.f;sb[1]=0.f;sb[2]=0.f;sb[3]=0.f;
            #pragma unroll
            for(int kc=0;kc<18;kc+=2){
                bf16x8 a0 = *(const bf16x8*)(Qrowbase + ((kc*64 + lhi*16) ^ qswz));
                bf16x8 b0 = *(const bf16x8*)(kf + kc*512);
                sa = __builtin_amdgcn_mfma_f32_16x16x32_bf16(a0, b0, sa, 0,0,0);
                bf16x8 a1 = *(const bf16x8*)(Qrowbase + (((kc+1)*64 + lhi*16) ^ qswz));
                bf16x8 b1 = *(const bf16x8*)(kf + (kc+1)*512);
                sb = __builtin_amdgcn_mfma_f32_16x16x32_bf16(a1, b1, sb, 0,0,0);
            }
            int pg = pfrag*16 + l15;
            #pragma unroll
            for(int r=0;r<4;++r){
                float sv = sa[r] + sb[r];
                if(pg == qg0 + r) sv -= 10000.f;
                float pv = __expf(sv);
                l_run[r] += pv;
                int row = qf*16 + lhi*4 + r;
                int col = ph*64 + s*16 + l15;
                *(unsigned short*)((char*)Ps + ((row*512 + col*2) ^ ((row&7)<<4))) = f2bf(pv);
            }
        }
        __syncthreads();   // Ps fully written
        // ---- PV phase: 32q x 128v over 256 p ----
        #pragma unroll
        for(int kc2g=0;kc2g<8;++kc2g){
            int pt = (p0>>6) + (kc2g>>1);
            int kc2 = kc2g&1;
            const unsigned short* vfp = VF + ((((size_t)(b*64 + pt)*64 + w*8)*2 + kc2)*64)*8 + lane*8;
            bf16x8 pa[2];
            #pragma unroll
            for(int qs=0;qs<2;++qs){
                int row = qs*16 + l15;
                pa[qs] = *(const bf16x8*)((const char*)Ps + ((row*512 + kc2g*64 + lhi*16) ^ ((row&7)<<4)));
            }
            #pragma unroll
            for(int vfi=0;vfi<8;++vfi){
                bf16x8 bv = *(const bf16x8*)(vfp + vfi*1024);
                #pragma unroll
                for(int qs=0;qs<2;++qs)
                    acc[qs][vfi] = __builtin_amdgcn_mfma_f32_16x16x32_bf16(pa[qs], bv, acc[qs][vfi], 0,0,0);
            }
        }
    }
    // l: reduce over 16 p-cols (l15) then over 4 ph-waves via LDS
    #pragma unroll
    for(int r=0;r<4;++r){
        float s = l_run[r];
        #pragma unroll
        for(int off=8;off>=1;off>>=1) s += __shfl_xor(s, off);
        if(l15==0) lpart[ph][qf*16 + lhi*4 + r] = s;
    }
    __syncthreads();
    float linv[2][4];
    #pragma unroll
    for(int qs=0;qs<2;++qs)
        #pragma unroll
        for(int r=0;r<4;++r){
            int qq = qs*16 + lhi*4 + r;
            linv[qs][r] = 0.25f / (lpart[0][qq]+lpart[1][qq]+lpart[2][qq]+lpart[3][qq]);
        }
    #pragma unroll
    for(int qs=0;qs<2;++qs){
        #pragma unroll
        for(int vfi=0;vfi<8;++vfi){
            int vg = w*128 + vfi*16 + l15;
            #pragma unroll
            for(int r=0;r<4;++r){
                att[((size_t)b*LQ + q0 + qs*16 + lhi*4 + r)*DV + vg] = f2bf(acc[qs][vfi][r] * linv[qs][r]);
            }
        }
    }
}

// K6: overlap-add att -> y0, 1x1 conv Wc -> y1, BN partial sums
__global__ __launch_bounds__(256) void k6_comb(const unsigned short* __restrict__ att, const float* __restrict__ Wc,
                                               float* __restrict__ y1, float* __restrict__ bnsum, float* __restrict__ bnsq){
    int Y = blockIdx.x, b = blockIdx.y;
    __shared__ float y0s[64][129];
    __shared__ float wcs[64][65];
    __shared__ float red1[4][64];
    __shared__ float red2[4][64];
    int t = threadIdx.x, lane = t&63, w = t>>6;
    for(int i=t;i<4096;i+=256){ int o=i&63, c=i>>6; wcs[c][o] = Wc[o*64+c]; }
    int ky0 = (Y+1)&1;
    int iA = (Y+1-ky0)>>1;
    int iB = (Y+1-ky0-2)>>1;
    bool vA = (iA>=0 && iA<64), vB = (iB>=0 && iB<64);
    size_t bb = (size_t)b*LQ;
    int vbase = lane*16;
    for(int xi=0;xi<32;++xi){
        int X = w*32+xi;
        int kx0 = (X+1)&1;
        int jA = (X+1-kx0)>>1, jB = (X+1-kx0-2)>>1;
        bool uA = (jA>=0 && jA<64), uB = (jB>=0 && jB<64);
        float s = 0.f;
        if(vA){
            if(uA) s += bf2f(att[(bb + iA*64 + jA)*DV + vbase + ky0*4 + kx0]);
            if(uB) s += bf2f(att[(bb + iA*64 + jB)*DV + vbase + ky0*4 + kx0+2]);
        }
        if(vB){
            if(uA) s += bf2f(att[(bb + iB*64 + jA)*DV + vbase + (ky0+2)*4 + kx0]);
            if(uB) s += bf2f(att[(bb + iB*64 + jB)*DV + vbase + (ky0+2)*4 + kx0+2]);
        }
        y0s[lane][X] = s;
    }
    __syncthreads();
    float s1 = 0.f, s2 = 0.f;
    float yv[32];
    for(int xi=0;xi<32;++xi){
        int X = w*32+xi;
        float a = 0.f;
        #pragma unroll 8
        for(int c=0;c<64;++c) a += wcs[c][lane]*y0s[c][X];
        yv[xi] = a; s1 += a; s2 += a*a;
    }
    __syncthreads();
    for(int xi=0;xi<32;++xi){ y0s[lane][w*32+xi] = yv[xi]; }
    red1[w][lane] = s1; red2[w][lane] = s2;
    __syncthreads();
    for(int i=t;i<8192;i+=256){
        int o=i>>7, X=i&127;
        y1[(((size_t)b*64+o)*128+Y)*128 + X] = y0s[o][X];
    }
    if(t<64){
        float a = red1[0][t]+red1[1][t]+red1[2][t]+red1[3][t];
        float c2 = red2[0][t]+red2[1][t]+red2[2][t]+red2[3][t];
        atomicAdd(&bnsum[t], a);
        atomicAdd(&bnsq[t], c2);
    }
}

// K7: BN finalize + alpha residual
__global__ __launch_bounds__(256) void k7_fin(const float* __restrict__ y1, const float* __restrict__ alpha,
                                              const float* __restrict__ bn_gamma, const float* __restrict__ bn_beta,
                                              const float* __restrict__ bnsum, const float* __restrict__ bnsq,
                                              float* __restrict__ out){
    const float invN = 1.f/65536.f;
    int idx = blockIdx.x*blockDim.x + threadIdx.x;
    int total = (4*64*128*128)/4;
    for(int i = idx; i < total; i += gridDim.x*blockDim.x){
        int e = i*4;
        int o = (e>>14)&63;
        float mu = bnsum[o]*invN;
        float var = bnsq[o]*invN - mu*mu;
        float sc = bn_gamma[o]*rsqrtf(var + 1e-5f);
        float bt = bn_beta[o];
        float4 yv = ((const float4*)y1)[i];
        float4 av = ((const float4*)alpha)[i];
        float4 r;
        r.x = sc*(yv.x-mu) + bt + av.x;
        r.y = sc*(yv.y-mu) + bt + av.y;
        r.z = sc*(yv.z-mu) + bt + av.z;
        r.w = sc*(yv.w-mu) + bt + av.w;
        ((float4*)out)[i] = r;
    }
}

extern "C" void kernel_launch(void* const* d_in, const int* in_sizes, int n_in,
                              void* d_out, int out_size, void* d_ws, size_t ws_size,
                              hipStream_t stream) {
    const float* f        = (const float*)d_in[0];
    const float* alpha    = (const float*)d_in[1];
    const float* gw       = (const float*)d_in[2];
    const float* gb       = (const float*)d_in[3];
    const float* Wc       = (const float*)d_in[4];
    const float* bn_gamma = (const float*)d_in[5];
    const float* bn_beta  = (const float*)d_in[6];
    float* out = (float*)d_out;
    char* ws = (char*)d_ws;

    float*          fd   = (float*)(ws + 0);                    //  4,194,304
    unsigned short* Wp   = (unsigned short*)(ws + 4194304);     // 18,874,368
    unsigned short* KF   = (unsigned short*)(ws + 23068672);    // 18,874,368
    unsigned short* VF   = (unsigned short*)(ws + 41943040);    // 33,554,432
    unsigned short* att  = (unsigned short*)(ws + 75497472);    // 33,554,432
    float*          y1   = (float*)(ws + 109051904);            // 16,777,216
    float*          bnsum= (float*)(ws + 125829120);            //        256
    float*          bnsq = (float*)(ws + 125829376);            //        256

    hipMemsetAsync(bnsum, 0, 512, stream);
    k1_fd   <<<dim3(64,4),   256, 0, stream>>>(f, gw, gb, fd);
    k2_wp   <<<dim3(64,4),   256, 0, stream>>>(fd, Wp, KF);
    k3_vf   <<<dim3(64,4,4), 256, 0, stream>>>(alpha, VF);
    k45d    <<<dim3(512),    512, 0, stream>>>(Wp, KF, VF, att);
    k6_comb <<<dim3(128,4),  256, 0, stream>>>(att, Wc, y1, bnsum, bnsq);
    k7_fin  <<<dim3(1024),   256, 0, stream>>>(y1, alpha, bn_gamma, bn_beta, bnsum, bnsq, out);
}